// Round 3
// baseline (195.028 us; speedup 1.0000x reference)
//
#include <hip/hip_runtime.h>
#include <hip/hip_bf16.h>
#include <math.h>

#define H   64
#define L   6
#define TE  32
#define SEL 64
#define CD  128
#define DC  128
#define KK  16
#define BB  32
#define NN  8192
#define EPSV 1e-6f

typedef float f32x4  __attribute__((ext_vector_type(4)));
typedef short bf16x8 __attribute__((ext_vector_type(8)));
typedef short bf16x4 __attribute__((ext_vector_type(4)));

__device__ __forceinline__ float swish_f(float v) {
    return v * __builtin_amdgcn_rcpf(1.0f + __expf(-v));
}
__device__ __forceinline__ short f2bf(float f) {
    __hip_bfloat16 h = __float2bfloat16(f);
    return *reinterpret_cast<short*>(&h);
}

#if __has_builtin(__builtin_amdgcn_mfma_f32_16x16x16_bf16_1k)
#define MFMA16(a, b, c) __builtin_amdgcn_mfma_f32_16x16x16_bf16_1k(a, b, c, 0, 0, 0)
#else
__device__ __forceinline__ f32x4 mfma16_asm(bf16x4 a, bf16x4 b, f32x4 c) {
    f32x4 d;
    asm("v_mfma_f32_16x16x16_bf16 %0, %1, %2, %3" : "=v"(d) : "v"(a), "v"(b), "v"(c));
    return d;
}
#define MFMA16(a, b, c) mfma16_asm(a, b, c)
#endif
#define MFMA32(a, b, c) __builtin_amdgcn_mfma_f32_16x16x32_bf16(a, b, c, 0, 0, 0)

// ws layout (shorts):
//   objffrag [32][2][64][8]          = 32768
//   tabfrag  [32][6][8][64][4]       = 393216   (16x16x16 A-frag, K=16 exact)
//   whfrag   [6][4][2][64][8]        = 24576
//   wpffrag  [4][2][64][8]           = 4096
#define OFF_OBJF 0
#define OFF_TAB  32768
#define OFF_WH   425984
#define OFF_WPF  450560

// ---------------------------------------------------------------------------
// Weight A-frags for 16x16x32: A[row=16t+(lane&15)][k=32s+8*(lane>>4)+jj]
// (matvec C = W^T h  ->  frag = W[k][row])
// ---------------------------------------------------------------------------
__global__ void setup_w(const float* __restrict__ W_h, const float* __restrict__ W_pf,
                        short* __restrict__ whfrag, short* __restrict__ wpffrag) {
    const int gid = blockIdx.x * 256 + threadIdx.x;     // 32 blocks -> 8192 threads
    for (int idx = gid; idx < 6 * 4 * 2 * 64 * 8; idx += 8192) {
        const int jj = idx & 7, lane = (idx >> 3) & 63, s = (idx >> 9) & 1,
                  t = (idx >> 10) & 3, l = idx >> 12;
        const int g = lane >> 4, row = 16 * t + (lane & 15), k = 32 * s + 8 * g + jj;
        whfrag[idx] = f2bf(W_h[(l * H + k) * H + row]);
    }
    for (int idx = gid; idx < 4 * 2 * 64 * 8; idx += 8192) {
        const int jj = idx & 7, lane = (idx >> 3) & 63, s = (idx >> 9) & 1, t = idx >> 10;
        const int g = lane >> 4, row = 16 * t + (lane & 15), k = 32 * s + 8 * g + jj;
        wpffrag[idx] = f2bf(W_pf[k * SEL + row]);
    }
}

// ---------------------------------------------------------------------------
// Per-(b,k) object setup: objf A-frag (affinity, 16x16x32) + folded tab A-frag
// (16x16x16: row=16u+(lane&15) is the 2H dim, k-dim=4*(lane>>4)+jj is object).
// ---------------------------------------------------------------------------
__global__ void setup_obj(const float* __restrict__ c, const float* __restrict__ t,
                          const float* __restrict__ W_of, const float* __restrict__ b_of,
                          const float* __restrict__ W_c1, const float* __restrict__ b_c1,
                          const float* __restrict__ W_c2, const float* __restrict__ b_c2,
                          const float* __restrict__ W_ss, const float* __restrict__ b_ss,
                          short* __restrict__ objffrag, short* __restrict__ tabfrag) {
    const int bk = blockIdx.x, b = bk >> 4, k = bk & 15;
    const int tid = threadIdx.x;                        // 0..127
    __shared__ float cwt[TE + DC];
    __shared__ float c1s[CD], c2s[CD];

    if (tid < 16) {
        float f   = __expf(-logf(10000.0f) * (float)tid * (1.0f / 15.0f));
        float arg = t[b] * f;
        cwt[tid]      = sinf(arg);
        cwt[tid + 16] = cosf(arg);
    }
    cwt[TE + tid] = c[(b * KK + k) * DC + tid];
    __syncthreads();

    if (tid < SEL) {   // object_features -> A-frag rows = object k, k-dim = tid
        float a = b_of[tid];
        for (int d = 0; d < TE + DC; ++d) a += cwt[d] * W_of[d * SEL + tid];
        a = swish_f(a);
        const int s = tid >> 5, g = (tid >> 3) & 3, jj = tid & 7;
        objffrag[(((b * 2 + s) * 64) + (16 * g + k)) * 8 + jj] = f2bf(a);
    }
    {
        float a = b_c1[tid];
        for (int d = 0; d < TE + DC; ++d) a += cwt[d] * W_c1[d * CD + tid];
        c1s[tid] = swish_f(a);
    }
    __syncthreads();
    {
        float a = b_c2[tid];
        for (int d = 0; d < CD; ++d) a += c1s[d] * W_c2[d * CD + tid];
        c2s[tid] = swish_f(a);
    }
    __syncthreads();

    // tab[l][j=tid] = c2 @ W_ss[l,:,j] + b_ss[l,j]
    // A-frag (16x16x16): u = j>>4, row = j&15, lane = 16*(k>>2)+row, jj = k&3
    const int u = tid >> 4, row = tid & 15, lane = 16 * (k >> 2) + row, jj = k & 3;
    for (int l = 0; l < L; ++l) {
        const float* W = W_ss + l * CD * (2 * H);
        float a = b_ss[l * (2 * H) + tid];
        for (int d = 0; d < CD; ++d) a += c2s[d] * W[d * (2 * H) + tid];
        tabfrag[(((b * 6 + l) * 8 + u) * 64 + lane) * 4 + jj] = f2bf(a);
    }
}

// ---------------------------------------------------------------------------
// Main: 1024 blocks x 256 threads (4 waves), ZERO barriers (hlds is
// wave-exclusive). A-frags loaded per-layer straight from global (L2-hot).
// ---------------------------------------------------------------------------
__global__ __launch_bounds__(256, 4) void main_kernel(
    const float* __restrict__ x,
    const float* __restrict__ W_emb, const float* __restrict__ b_emb,
    const float* __restrict__ b_pf,  const float* __restrict__ b_h,
    const float* __restrict__ ln_g,  const float* __restrict__ ln_b,
    const float* __restrict__ W_out, const float* __restrict__ b_out,
    const short* __restrict__ objffrag, const short* __restrict__ tabfrag,
    const short* __restrict__ whfrag,   const short* __restrict__ wpffrag,
    float* __restrict__ out) {

    __shared__ short hlds[256 * 72];        // [point][dim], stride 72 shorts

    const int tid  = threadIdx.x;
    const int wave = tid >> 6, lane = tid & 63;
    const int p = lane & 15, g = lane >> 4;
    const int b = blockIdx.x >> 5;
    const int point0 = (blockIdx.x & 31) << 8;

    bf16x8 wpfr[4][2], objr[2];
#pragma unroll
    for (int t = 0; t < 4; ++t)
#pragma unroll
        for (int s = 0; s < 2; ++s)
            wpfr[t][s] = *(const bf16x8*)&wpffrag[(((t * 2 + s) * 64) + lane) * 8];
#pragma unroll
    for (int s = 0; s < 2; ++s)
        objr[s] = *(const bf16x8*)&objffrag[(((b * 2 + s) * 64) + lane) * 8];

    bf16x4 swfrag[4];

    // ---------------- Phase A ----------------
#pragma unroll
    for (int i = 0; i < 4; ++i) {
        const int tloc = (wave * 4 + i) * 16 + p;
        const int ptg  = b * NN + point0 + tloc;
        const float x0 = x[ptg * 3 + 0], x1 = x[ptg * 3 + 1], x2 = x[ptg * 3 + 2];

        float  ev[2][8];
        bf16x8 eb[2];
#pragma unroll
        for (int s = 0; s < 2; ++s)
#pragma unroll
            for (int jj = 0; jj < 8; ++jj) {
                const int k = 32 * s + 8 * g + jj;
                float e = b_emb[k] + x0 * W_emb[k] + x1 * W_emb[H + k] + x2 * W_emb[2 * H + k];
                ev[s][jj] = e;
                eb[s][jj] = f2bf(e);
            }

        // pf matvec, bias folded into C-init
        f32x4 macc[4];
#pragma unroll
        for (int t = 0; t < 4; ++t) {
            const float4 bp = *(const float4*)&b_pf[16 * t + 4 * g];
            f32x4 m; m[0] = bp.x; m[1] = bp.y; m[2] = bp.z; m[3] = bp.w;
            m = MFMA32(wpfr[t][0], eb[0], m);
            m = MFMA32(wpfr[t][1], eb[1], m);
            macc[t] = m;
        }
#pragma unroll
        for (int t = 0; t < 4; ++t) {
            short4 w;
            w.x = f2bf(swish_f(macc[t][0]));
            w.y = f2bf(swish_f(macc[t][1]));
            w.z = f2bf(swish_f(macc[t][2]));
            w.w = f2bf(swish_f(macc[t][3]));
            *(short4*)&hlds[tloc * 72 + 16 * t + 4 * g] = w;
        }
        bf16x8 pfb[2];
#pragma unroll
        for (int s = 0; s < 2; ++s)
            pfb[s] = *(bf16x8*)&hlds[tloc * 72 + 32 * s + 8 * g];

        // affinity: C[obj=4g+r][point=p]
        f32x4 aacc = {0.f, 0.f, 0.f, 0.f};
#pragma unroll
        for (int s = 0; s < 2; ++s)
            aacc = MFMA32(objr[s], pfb[s], aacc);

        // softmax over 16 objects
        float mx = fmaxf(fmaxf(aacc[0], aacc[1]), fmaxf(aacc[2], aacc[3]));
        mx = fmaxf(mx, __shfl_xor(mx, 16));
        mx = fmaxf(mx, __shfl_xor(mx, 32));
        float swv[4], ss = 0.f;
#pragma unroll
        for (int r = 0; r < 4; ++r) { swv[r] = __expf(aacc[r] - mx); ss += swv[r]; }
        ss += __shfl_xor(ss, 16);
        ss += __shfl_xor(ss, 32);
        const float inv = __builtin_amdgcn_rcpf(ss);

        // C-layout (obj=4g+r) IS the 16x16x16 B-frag layout (k=4g+jj): no shuffles
        bf16x4 sf;
#pragma unroll
        for (int r = 0; r < 4; ++r) sf[r] = f2bf(swv[r] * inv);
        swfrag[i] = sf;

        // h0 = swish(x_embed) in B-frag positions
#pragma unroll
        for (int s = 0; s < 2; ++s) {
            bf16x8 hb;
#pragma unroll
            for (int jj = 0; jj < 8; ++jj) hb[jj] = f2bf(swish_f(ev[s][jj]));
            *(bf16x8*)&hlds[tloc * 72 + 32 * s + 8 * g] = hb;
        }
    }

    // ---------------- AdaLN layers (no barriers) ----------------
    for (int l = 0; l < L; ++l) {
        bf16x8 whr[4][2];
        bf16x4 tabr[8];
#pragma unroll
        for (int t = 0; t < 4; ++t)
#pragma unroll
            for (int s = 0; s < 2; ++s)
                whr[t][s] = *(const bf16x8*)&whfrag[((l * 8 + t * 2 + s) * 64 + lane) * 8];
#pragma unroll
        for (int u = 0; u < 8; ++u)
            tabr[u] = *(const bf16x4*)&tabfrag[(((b * 6 + l) * 8 + u) * 64 + lane) * 4];

#pragma unroll
        for (int i = 0; i < 4; ++i) {
            const int tloc = (wave * 4 + i) * 16 + p;
            const bf16x8 hb0 = *(bf16x8*)&hlds[tloc * 72 + 8 * g];
            const bf16x8 hb1 = *(bf16x8*)&hlds[tloc * 72 + 32 + 8 * g];
            const bf16x4 sf  = swfrag[i];

            // sel-mix first (independent of hb): scale u=0..3, shift u=4..7
            f32x4 sacc[8];
#pragma unroll
            for (int u = 0; u < 8; ++u) {
                f32x4 z = {0.f, 0.f, 0.f, 0.f};
                sacc[u] = MFMA16(tabr[u], sf, z);
            }

            // matvec, bias folded into C-init
            f32x4 macc[4];
#pragma unroll
            for (int t = 0; t < 4; ++t) {
                const float4 bh = *(const float4*)&b_h[l * H + 16 * t + 4 * g];
                f32x4 m; m[0] = bh.x; m[1] = bh.y; m[2] = bh.z; m[3] = bh.w;
                m = MFMA32(whr[t][0], hb0, m);
                m = MFMA32(whr[t][1], hb1, m);
                macc[t] = m;
            }

            float hn[4][4], s1 = 0.f, s2 = 0.f;
#pragma unroll
            for (int t = 0; t < 4; ++t)
#pragma unroll
                for (int r = 0; r < 4; ++r) {
                    const float v = swish_f(macc[t][r]);
                    hn[t][r] = v; s1 += v; s2 += v * v;
                }
            s1 += __shfl_xor(s1, 16); s1 += __shfl_xor(s1, 32);
            s2 += __shfl_xor(s2, 16); s2 += __shfl_xor(s2, 32);
            const float mu  = s1 * (1.0f / 64.0f);
            const float var = s2 * (1.0f / 64.0f) - mu * mu;
            const float rin = rsqrtf(var + EPSV);

            if (l < L - 1) {
#pragma unroll
                for (int t = 0; t < 4; ++t) {
                    const float4 gg = *(const float4*)&ln_g[l * H + 16 * t + 4 * g];
                    const float4 bb = *(const float4*)&ln_b[l * H + 16 * t + 4 * g];
                    float ggv[4]; ggv[0] = gg.x; ggv[1] = gg.y; ggv[2] = gg.z; ggv[3] = gg.w;
                    float bbv[4]; bbv[0] = bb.x; bbv[1] = bb.y; bbv[2] = bb.z; bbv[3] = bb.w;
                    short wv[4];
#pragma unroll
                    for (int r = 0; r < 4; ++r) {
                        const float lnv = (hn[t][r] - mu) * rin * ggv[r] + bbv[r];
                        wv[r] = f2bf(lnv * (1.0f + sacc[t][r]) + sacc[4 + t][r]);
                    }
                    short4 w; w.x = wv[0]; w.y = wv[1]; w.z = wv[2]; w.w = wv[3];
                    *(short4*)&hlds[tloc * 72 + 16 * t + 4 * g] = w;
                }
            } else {
                float d0 = 0.f, d1 = 0.f, d2 = 0.f;
#pragma unroll
                for (int t = 0; t < 4; ++t) {
                    const float4 gg = *(const float4*)&ln_g[l * H + 16 * t + 4 * g];
                    const float4 bb = *(const float4*)&ln_b[l * H + 16 * t + 4 * g];
                    float ggv[4]; ggv[0] = gg.x; ggv[1] = gg.y; ggv[2] = gg.z; ggv[3] = gg.w;
                    float bbv[4]; bbv[0] = bb.x; bbv[1] = bb.y; bbv[2] = bb.z; bbv[3] = bb.w;
                    const float4 w0 = *(const float4*)&W_out[(16 * t + 4 * g) * 3];
                    const float4 w1 = *(const float4*)&W_out[(16 * t + 4 * g) * 3 + 4];
                    const float4 w2 = *(const float4*)&W_out[(16 * t + 4 * g) * 3 + 8];
                    float wv[12];
                    wv[0] = w0.x; wv[1] = w0.y; wv[2]  = w0.z; wv[3]  = w0.w;
                    wv[4] = w1.x; wv[5] = w1.y; wv[6]  = w1.z; wv[7]  = w1.w;
                    wv[8] = w2.x; wv[9] = w2.y; wv[10] = w2.z; wv[11] = w2.w;
#pragma unroll
                    for (int r = 0; r < 4; ++r) {
                        const float lnv = (hn[t][r] - mu) * rin * ggv[r] + bbv[r];
                        const float hv  = lnv * (1.0f + sacc[t][r]) + sacc[4 + t][r];
                        d0 += hv * wv[r * 3 + 0];
                        d1 += hv * wv[r * 3 + 1];
                        d2 += hv * wv[r * 3 + 2];
                    }
                }
                d0 += __shfl_xor(d0, 16); d0 += __shfl_xor(d0, 32);
                d1 += __shfl_xor(d1, 16); d1 += __shfl_xor(d1, 32);
                d2 += __shfl_xor(d2, 16); d2 += __shfl_xor(d2, 32);
                if (g == 0) {
                    const int ptg = b * NN + point0 + tloc;
                    out[ptg * 3 + 0] = d0 + b_out[0];
                    out[ptg * 3 + 1] = d1 + b_out[1];
                    out[ptg * 3 + 2] = d2 + b_out[2];
                }
            }
        }
    }
}

extern "C" void kernel_launch(void* const* d_in, const int* in_sizes, int n_in,
                              void* d_out, int out_size, void* d_ws, size_t ws_size,
                              hipStream_t stream) {
    const float* x     = (const float*)d_in[0];
    const float* c     = (const float*)d_in[1];
    const float* t     = (const float*)d_in[2];
    const float* W_emb = (const float*)d_in[3];
    const float* b_emb = (const float*)d_in[4];
    const float* W_pf  = (const float*)d_in[5];
    const float* b_pf  = (const float*)d_in[6];
    const float* W_of  = (const float*)d_in[7];
    const float* b_of  = (const float*)d_in[8];
    const float* W_c1  = (const float*)d_in[9];
    const float* b_c1  = (const float*)d_in[10];
    const float* W_c2  = (const float*)d_in[11];
    const float* b_c2  = (const float*)d_in[12];
    const float* W_h   = (const float*)d_in[13];
    const float* b_h   = (const float*)d_in[14];
    const float* W_ss  = (const float*)d_in[15];
    const float* b_ss  = (const float*)d_in[16];
    const float* ln_g  = (const float*)d_in[17];
    const float* ln_b  = (const float*)d_in[18];
    const float* W_out = (const float*)d_in[19];
    const float* b_out = (const float*)d_in[20];
    float* out = (float*)d_out;

    short* wsb      = (short*)d_ws;
    short* objffrag = wsb + OFF_OBJF;
    short* tabfrag  = wsb + OFF_TAB;
    short* whfrag   = wsb + OFF_WH;
    short* wpffrag  = wsb + OFF_WPF;

    setup_w<<<32, 256, 0, stream>>>(W_h, W_pf, whfrag, wpffrag);
    setup_obj<<<BB * KK, 128, 0, stream>>>(c, t, W_of, b_of, W_c1, b_c1,
                                           W_c2, b_c2, W_ss, b_ss, objffrag, tabfrag);
    main_kernel<<<1024, 256, 0, stream>>>(x, W_emb, b_emb, b_pf, b_h, ln_g, ln_b,
                                          W_out, b_out, objffrag, tabfrag,
                                          whfrag, wpffrag, out);
}

// Round 5
// 173.304 us; speedup vs baseline: 1.1254x; 1.1254x over previous
//
#include <hip/hip_runtime.h>
#include <hip/hip_bf16.h>
#include <math.h>

#define H   64
#define L   6
#define TE  32
#define SEL 64
#define CD  128
#define DC  128
#define KK  16
#define BB  32
#define NN  8192
#define EPSV 1e-6f

typedef float f32x4  __attribute__((ext_vector_type(4)));
typedef short bf16x8 __attribute__((ext_vector_type(8)));

__device__ __forceinline__ float swish_f(float v) {
    return v * __builtin_amdgcn_rcpf(1.0f + __expf(-v));
}
__device__ __forceinline__ short f2bf(float f) {
    __hip_bfloat16 h = __float2bfloat16(f);
    return *reinterpret_cast<short*>(&h);
}

#define MFMA32(a, b, c) __builtin_amdgcn_mfma_f32_16x16x32_bf16(a, b, c, 0, 0, 0)

// ws layout (shorts):
//   objffrag [32][2][64][8]     = 32768
//   tabfrag  [32][6][8][64][8]  = 786432   (16x16x32 A-frag, obj K padded to 32)
//   whfrag   [6][4][2][64][8]   = 24576
//   wpffrag  [4][2][64][8]      = 4096
#define OFF_OBJF 0
#define OFF_TAB  32768
#define OFF_WH   819200
#define OFF_WPF  843776

// ---------------------------------------------------------------------------
// Weight A-frags for 16x16x32: A[row=16t+(lane&15)][k=32s+8*(lane>>4)+jj]
// (matvec C = W^T h  ->  frag = W[k][row]). Also zero-fills tabfrag lanes
// 32..63 (object index K=16 padded to 32).
// ---------------------------------------------------------------------------
__global__ void setup_w(const float* __restrict__ W_h, const float* __restrict__ W_pf,
                        short* __restrict__ whfrag, short* __restrict__ wpffrag,
                        short* __restrict__ tabfrag) {
    const int gid = blockIdx.x * 256 + threadIdx.x;     // 64 blocks -> 16384 threads
    for (int idx = gid; idx < 6 * 4 * 2 * 64 * 8; idx += 16384) {
        const int jj = idx & 7, lane = (idx >> 3) & 63, s = (idx >> 9) & 1,
                  t = (idx >> 10) & 3, l = idx >> 12;
        const int g = lane >> 4, row = 16 * t + (lane & 15), k = 32 * s + 8 * g + jj;
        whfrag[idx] = f2bf(W_h[(l * H + k) * H + row]);
    }
    for (int idx = gid; idx < 4 * 2 * 64 * 8; idx += 16384) {
        const int jj = idx & 7, lane = (idx >> 3) & 63, s = (idx >> 9) & 1, t = idx >> 10;
        const int g = lane >> 4, row = 16 * t + (lane & 15), k = 32 * s + 8 * g + jj;
        wpffrag[idx] = f2bf(W_pf[k * SEL + row]);
    }
    for (int idx = gid; idx < 32 * 6 * 8 * 32 * 8; idx += 16384) {
        const int jj = idx & 7, lane32 = (idx >> 3) & 31, t = (idx >> 8) & 7, bl = idx >> 11;
        tabfrag[((bl * 8 + t) * 64 + 32 + lane32) * 8 + jj] = 0;
    }
}

// ---------------------------------------------------------------------------
// Per-(b,k) object setup: objf A-frag (affinity) + folded scale/shift table
// A-frag (tab^T): row = 2H dim, k-dim = object index (valid k<16 -> lanes 0..31).
// ---------------------------------------------------------------------------
__global__ void setup_obj(const float* __restrict__ c, const float* __restrict__ t,
                          const float* __restrict__ W_of, const float* __restrict__ b_of,
                          const float* __restrict__ W_c1, const float* __restrict__ b_c1,
                          const float* __restrict__ W_c2, const float* __restrict__ b_c2,
                          const float* __restrict__ W_ss, const float* __restrict__ b_ss,
                          short* __restrict__ objffrag, short* __restrict__ tabfrag) {
    const int bk = blockIdx.x, b = bk >> 4, k = bk & 15;
    const int tid = threadIdx.x;                        // 0..127
    __shared__ float cwt[TE + DC];
    __shared__ float c1s[CD], c2s[CD];

    if (tid < 16) {
        float f   = __expf(-logf(10000.0f) * (float)tid * (1.0f / 15.0f));
        float arg = t[b] * f;
        cwt[tid]      = sinf(arg);
        cwt[tid + 16] = cosf(arg);
    }
    cwt[TE + tid] = c[(b * KK + k) * DC + tid];
    __syncthreads();

    if (tid < SEL) {   // object_features -> A-frag rows = object k, k-dim = tid
        float a = b_of[tid];
        for (int d = 0; d < TE + DC; ++d) a += cwt[d] * W_of[d * SEL + tid];
        a = swish_f(a);
        const int s = tid >> 5, g = (tid >> 3) & 3, jj = tid & 7;
        objffrag[(((b * 2 + s) * 64) + (16 * g + k)) * 8 + jj] = f2bf(a);
    }
    {
        float a = b_c1[tid];
        for (int d = 0; d < TE + DC; ++d) a += cwt[d] * W_c1[d * CD + tid];
        c1s[tid] = swish_f(a);
    }
    __syncthreads();
    {
        float a = b_c2[tid];
        for (int d = 0; d < CD; ++d) a += c1s[d] * W_c2[d * CD + tid];
        c2s[tid] = swish_f(a);
    }
    __syncthreads();

    // tab[l][j=tid] = c2 @ W_ss[l,:,j] + b_ss[l,j]; A-frag: row=j, k-dim=k
    const int tt = tid >> 4, pp = tid & 15, lane = 16 * (k >> 3) + pp, jj = k & 7;
    for (int l = 0; l < L; ++l) {
        const float* W = W_ss + l * CD * (2 * H);
        float a = b_ss[l * (2 * H) + tid];
        for (int d = 0; d < CD; ++d) a += c2s[d] * W[d * (2 * H) + tid];
        tabfrag[((((b * 6 + l) * 8 + tt) * 64) + lane) * 8 + jj] = f2bf(a);
    }
}

// ---------------------------------------------------------------------------
// Main: 1024 blocks x 256 threads (4 waves), ZERO barriers (hlds is
// wave-exclusive). A-frags loaded per-layer straight from global (L2-hot).
// __launch_bounds__(256,3): ~168 reg budget > ~165 live set -> no spills.
// ((256,4) = 128-reg cap spilled in R3; inline-asm MFMA16 removed in R5 —
// regalloc-dependent D/A-B overlap corrupted results in R4.)
// ---------------------------------------------------------------------------
__global__ __launch_bounds__(256, 3) void main_kernel(
    const float* __restrict__ x,
    const float* __restrict__ W_emb, const float* __restrict__ b_emb,
    const float* __restrict__ b_pf,  const float* __restrict__ b_h,
    const float* __restrict__ ln_g,  const float* __restrict__ ln_b,
    const float* __restrict__ W_out, const float* __restrict__ b_out,
    const short* __restrict__ objffrag, const short* __restrict__ tabfrag,
    const short* __restrict__ whfrag,   const short* __restrict__ wpffrag,
    float* __restrict__ out) {

    __shared__ short hlds[256 * 72];        // [point][dim], stride 72 shorts

    const int tid  = threadIdx.x;
    const int wave = tid >> 6, lane = tid & 63;
    const int p = lane & 15, g = lane >> 4;
    const int b = blockIdx.x >> 5;
    const int point0 = (blockIdx.x & 31) << 8;

    bf16x8 wpfr[4][2], objr[2];
#pragma unroll
    for (int t = 0; t < 4; ++t)
#pragma unroll
        for (int s = 0; s < 2; ++s)
            wpfr[t][s] = *(const bf16x8*)&wpffrag[(((t * 2 + s) * 64) + lane) * 8];
#pragma unroll
    for (int s = 0; s < 2; ++s)
        objr[s] = *(const bf16x8*)&objffrag[(((b * 2 + s) * 64) + lane) * 8];

    bf16x8 swfrag[4];

    // ---------------- Phase A ----------------
#pragma unroll
    for (int i = 0; i < 4; ++i) {
        const int tloc = (wave * 4 + i) * 16 + p;
        const int ptg  = b * NN + point0 + tloc;
        const float x0 = x[ptg * 3 + 0], x1 = x[ptg * 3 + 1], x2 = x[ptg * 3 + 2];

        float  ev[2][8];
        bf16x8 eb[2];
#pragma unroll
        for (int s = 0; s < 2; ++s)
#pragma unroll
            for (int jj = 0; jj < 8; ++jj) {
                const int k = 32 * s + 8 * g + jj;
                float e = b_emb[k] + x0 * W_emb[k] + x1 * W_emb[H + k] + x2 * W_emb[2 * H + k];
                ev[s][jj] = e;
                eb[s][jj] = f2bf(e);
            }

        // pf matvec, bias folded into C-init
        f32x4 macc[4];
#pragma unroll
        for (int t = 0; t < 4; ++t) {
            const float4 bp = *(const float4*)&b_pf[16 * t + 4 * g];
            f32x4 m; m[0] = bp.x; m[1] = bp.y; m[2] = bp.z; m[3] = bp.w;
            m = MFMA32(wpfr[t][0], eb[0], m);
            m = MFMA32(wpfr[t][1], eb[1], m);
            macc[t] = m;
        }
#pragma unroll
        for (int t = 0; t < 4; ++t) {
            short4 w;
            w.x = f2bf(swish_f(macc[t][0]));
            w.y = f2bf(swish_f(macc[t][1]));
            w.z = f2bf(swish_f(macc[t][2]));
            w.w = f2bf(swish_f(macc[t][3]));
            *(short4*)&hlds[tloc * 72 + 16 * t + 4 * g] = w;
        }
        bf16x8 pfb[2];
#pragma unroll
        for (int s = 0; s < 2; ++s)
            pfb[s] = *(bf16x8*)&hlds[tloc * 72 + 32 * s + 8 * g];

        // affinity: C[obj=4g+r][point=p]
        f32x4 aacc = {0.f, 0.f, 0.f, 0.f};
#pragma unroll
        for (int s = 0; s < 2; ++s)
            aacc = MFMA32(objr[s], pfb[s], aacc);

        // softmax over 16 objects
        float mx = fmaxf(fmaxf(aacc[0], aacc[1]), fmaxf(aacc[2], aacc[3]));
        mx = fmaxf(mx, __shfl_xor(mx, 16));
        mx = fmaxf(mx, __shfl_xor(mx, 32));
        float swv[4], ss = 0.f;
#pragma unroll
        for (int r = 0; r < 4; ++r) { swv[r] = __expf(aacc[r] - mx); ss += swv[r]; }
        ss += __shfl_xor(ss, 16);
        ss += __shfl_xor(ss, 32);
        const float inv = __builtin_amdgcn_rcpf(ss);

        // redistribute to B-frag: lane needs sw[k], k=8g+jj (k<16 valid)
        bf16x8 sf;
#pragma unroll
        for (int jj = 0; jj < 8; ++jj) {
            const int k = 8 * g + jj;
            const float v = __shfl(swv[jj & 3], p + 16 * ((k >> 2) & 3)) * inv;
            sf[jj] = (g < 2) ? f2bf(v) : (short)0;
        }
        swfrag[i] = sf;

        // h0 = swish(x_embed) in B-frag positions
#pragma unroll
        for (int s = 0; s < 2; ++s) {
            bf16x8 hb;
#pragma unroll
            for (int jj = 0; jj < 8; ++jj) hb[jj] = f2bf(swish_f(ev[s][jj]));
            *(bf16x8*)&hlds[tloc * 72 + 32 * s + 8 * g] = hb;
        }
    }

    // ---------------- AdaLN layers (no barriers) ----------------
    for (int l = 0; l < L; ++l) {
        bf16x8 whr[4][2], tabr[8];
#pragma unroll
        for (int t = 0; t < 4; ++t)
#pragma unroll
            for (int s = 0; s < 2; ++s)
                whr[t][s] = *(const bf16x8*)&whfrag[((l * 8 + t * 2 + s) * 64 + lane) * 8];
#pragma unroll
        for (int u = 0; u < 8; ++u)
            tabr[u] = *(const bf16x8*)&tabfrag[(((b * 6 + l) * 8 + u) * 64 + lane) * 8];

#pragma unroll
        for (int i = 0; i < 4; ++i) {
            const int tloc = (wave * 4 + i) * 16 + p;
            const bf16x8 hb0 = *(bf16x8*)&hlds[tloc * 72 + 8 * g];
            const bf16x8 hb1 = *(bf16x8*)&hlds[tloc * 72 + 32 + 8 * g];
            const bf16x8 sf  = swfrag[i];

            // sel-mix (independent of hb): scale u=0..3, shift u=4..7
            f32x4 sacc[8];
#pragma unroll
            for (int u = 0; u < 8; ++u) {
                f32x4 z = {0.f, 0.f, 0.f, 0.f};
                sacc[u] = MFMA32(tabr[u], sf, z);
            }

            // matvec, bias folded into C-init
            f32x4 macc[4];
#pragma unroll
            for (int t = 0; t < 4; ++t) {
                const float4 bh = *(const float4*)&b_h[l * H + 16 * t + 4 * g];
                f32x4 m; m[0] = bh.x; m[1] = bh.y; m[2] = bh.z; m[3] = bh.w;
                m = MFMA32(whr[t][0], hb0, m);
                m = MFMA32(whr[t][1], hb1, m);
                macc[t] = m;
            }

            float hn[4][4], s1 = 0.f, s2 = 0.f;
#pragma unroll
            for (int t = 0; t < 4; ++t)
#pragma unroll
                for (int r = 0; r < 4; ++r) {
                    const float v = swish_f(macc[t][r]);
                    hn[t][r] = v; s1 += v; s2 += v * v;
                }
            s1 += __shfl_xor(s1, 16); s1 += __shfl_xor(s1, 32);
            s2 += __shfl_xor(s2, 16); s2 += __shfl_xor(s2, 32);
            const float mu  = s1 * (1.0f / 64.0f);
            const float var = s2 * (1.0f / 64.0f) - mu * mu;
            const float rin = rsqrtf(var + EPSV);

            if (l < L - 1) {
#pragma unroll
                for (int t = 0; t < 4; ++t) {
                    const float4 gg = *(const float4*)&ln_g[l * H + 16 * t + 4 * g];
                    const float4 bb = *(const float4*)&ln_b[l * H + 16 * t + 4 * g];
                    float ggv[4]; ggv[0] = gg.x; ggv[1] = gg.y; ggv[2] = gg.z; ggv[3] = gg.w;
                    float bbv[4]; bbv[0] = bb.x; bbv[1] = bb.y; bbv[2] = bb.z; bbv[3] = bb.w;
                    short wv[4];
#pragma unroll
                    for (int r = 0; r < 4; ++r) {
                        const float lnv = (hn[t][r] - mu) * rin * ggv[r] + bbv[r];
                        wv[r] = f2bf(lnv * (1.0f + sacc[t][r]) + sacc[4 + t][r]);
                    }
                    short4 w; w.x = wv[0]; w.y = wv[1]; w.z = wv[2]; w.w = wv[3];
                    *(short4*)&hlds[tloc * 72 + 16 * t + 4 * g] = w;
                }
            } else {
                float d0 = 0.f, d1 = 0.f, d2 = 0.f;
#pragma unroll
                for (int t = 0; t < 4; ++t) {
                    const float4 gg = *(const float4*)&ln_g[l * H + 16 * t + 4 * g];
                    const float4 bb = *(const float4*)&ln_b[l * H + 16 * t + 4 * g];
                    float ggv[4]; ggv[0] = gg.x; ggv[1] = gg.y; ggv[2] = gg.z; ggv[3] = gg.w;
                    float bbv[4]; bbv[0] = bb.x; bbv[1] = bb.y; bbv[2] = bb.z; bbv[3] = bb.w;
                    const float4 w0 = *(const float4*)&W_out[(16 * t + 4 * g) * 3];
                    const float4 w1 = *(const float4*)&W_out[(16 * t + 4 * g) * 3 + 4];
                    const float4 w2 = *(const float4*)&W_out[(16 * t + 4 * g) * 3 + 8];
                    float wv[12];
                    wv[0] = w0.x; wv[1] = w0.y; wv[2]  = w0.z; wv[3]  = w0.w;
                    wv[4] = w1.x; wv[5] = w1.y; wv[6]  = w1.z; wv[7]  = w1.w;
                    wv[8] = w2.x; wv[9] = w2.y; wv[10] = w2.z; wv[11] = w2.w;
#pragma unroll
                    for (int r = 0; r < 4; ++r) {
                        const float lnv = (hn[t][r] - mu) * rin * ggv[r] + bbv[r];
                        const float hv  = lnv * (1.0f + sacc[t][r]) + sacc[4 + t][r];
                        d0 += hv * wv[r * 3 + 0];
                        d1 += hv * wv[r * 3 + 1];
                        d2 += hv * wv[r * 3 + 2];
                    }
                }
                d0 += __shfl_xor(d0, 16); d0 += __shfl_xor(d0, 32);
                d1 += __shfl_xor(d1, 16); d1 += __shfl_xor(d1, 32);
                d2 += __shfl_xor(d2, 16); d2 += __shfl_xor(d2, 32);
                if (g == 0) {
                    const int ptg = b * NN + point0 + tloc;
                    out[ptg * 3 + 0] = d0 + b_out[0];
                    out[ptg * 3 + 1] = d1 + b_out[1];
                    out[ptg * 3 + 2] = d2 + b_out[2];
                }
            }
        }
    }
}

extern "C" void kernel_launch(void* const* d_in, const int* in_sizes, int n_in,
                              void* d_out, int out_size, void* d_ws, size_t ws_size,
                              hipStream_t stream) {
    const float* x     = (const float*)d_in[0];
    const float* c     = (const float*)d_in[1];
    const float* t     = (const float*)d_in[2];
    const float* W_emb = (const float*)d_in[3];
    const float* b_emb = (const float*)d_in[4];
    const float* W_pf  = (const float*)d_in[5];
    const float* b_pf  = (const float*)d_in[6];
    const float* W_of  = (const float*)d_in[7];
    const float* b_of  = (const float*)d_in[8];
    const float* W_c1  = (const float*)d_in[9];
    const float* b_c1  = (const float*)d_in[10];
    const float* W_c2  = (const float*)d_in[11];
    const float* b_c2  = (const float*)d_in[12];
    const float* W_h   = (const float*)d_in[13];
    const float* b_h   = (const float*)d_in[14];
    const float* W_ss  = (const float*)d_in[15];
    const float* b_ss  = (const float*)d_in[16];
    const float* ln_g  = (const float*)d_in[17];
    const float* ln_b  = (const float*)d_in[18];
    const float* W_out = (const float*)d_in[19];
    const float* b_out = (const float*)d_in[20];
    float* out = (float*)d_out;

    short* wsb      = (short*)d_ws;
    short* objffrag = wsb + OFF_OBJF;
    short* tabfrag  = wsb + OFF_TAB;
    short* whfrag   = wsb + OFF_WH;
    short* wpffrag  = wsb + OFF_WPF;

    setup_w<<<64, 256, 0, stream>>>(W_h, W_pf, whfrag, wpffrag, tabfrag);
    setup_obj<<<BB * KK, 128, 0, stream>>>(c, t, W_of, b_of, W_c1, b_c1,
                                           W_c2, b_c2, W_ss, b_ss, objffrag, tabfrag);
    main_kernel<<<1024, 256, 0, stream>>>(x, W_emb, b_emb, b_pf, b_h, ln_g, ln_b,
                                          W_out, b_out, objffrag, tabfrag,
                                          whfrag, wpffrag, out);
}

// Round 6
// 116.669 us; speedup vs baseline: 1.6716x; 1.4854x over previous
//
#include <hip/hip_runtime.h>
#include <hip/hip_bf16.h>
#include <math.h>

#define H   64
#define L   6
#define TE  32
#define SEL 64
#define CD  128
#define DC  128
#define KK  16
#define BB  32
#define NN  8192
#define EPSV 1e-6f

typedef float f32x4  __attribute__((ext_vector_type(4)));
typedef short bf16x8 __attribute__((ext_vector_type(8)));
typedef short bf16x4 __attribute__((ext_vector_type(4)));

__device__ __forceinline__ float swish_f(float v) {
    return v * __builtin_amdgcn_rcpf(1.0f + __expf(-v));
}
__device__ __forceinline__ short f2bf(float f) {
    __hip_bfloat16 h = __float2bfloat16(f);
    return *reinterpret_cast<short*>(&h);
}

// 16x16x16 bf16 MFMA: correct builtin spelling is ...16x16x16bf16_1k.
// Fallback: inline asm with EARLY-CLOBBER dest ("=&v") so D never aliases
// A/B/C (R4's silent corruption was regalloc overlapping D with a source).
#if __has_builtin(__builtin_amdgcn_mfma_f32_16x16x16bf16_1k)
#define MFMA16(a, b, c) __builtin_amdgcn_mfma_f32_16x16x16bf16_1k(a, b, c, 0, 0, 0)
#else
__device__ __forceinline__ f32x4 mfma16_asm(bf16x4 a, bf16x4 b, f32x4 c) {
    f32x4 d;
    asm("v_mfma_f32_16x16x16_bf16 %0, %1, %2, %3" : "=&v"(d) : "v"(a), "v"(b), "v"(c));
    return d;
}
#define MFMA16(a, b, c) mfma16_asm(a, b, c)
#endif
#define MFMA32(a, b, c) __builtin_amdgcn_mfma_f32_16x16x32_bf16(a, b, c, 0, 0, 0)

// ws layout (shorts):
//   objffrag [32][2][64][8]     = 32768
//   tabfrag  [32][6][8][64][4]  = 393216   (16x16x16 A-frag, K=16 exact)
//   whfrag   [6][4][2][64][8]   = 24576
//   wpffrag  [4][2][64][8]      = 4096
#define OFF_OBJF 0
#define OFF_TAB  32768
#define OFF_WH   425984
#define OFF_WPF  450560

// ---------------------------------------------------------------------------
// Weight A-frags for 16x16x32: A[row=16t+(lane&15)][k=32s+8*(lane>>4)+jj]
// (matvec C = W^T h  ->  frag = W[k][row])
// ---------------------------------------------------------------------------
__global__ void setup_w(const float* __restrict__ W_h, const float* __restrict__ W_pf,
                        short* __restrict__ whfrag, short* __restrict__ wpffrag) {
    const int gid = blockIdx.x * 256 + threadIdx.x;     // 32 blocks -> 8192 threads
    for (int idx = gid; idx < 6 * 4 * 2 * 64 * 8; idx += 8192) {
        const int jj = idx & 7, lane = (idx >> 3) & 63, s = (idx >> 9) & 1,
                  t = (idx >> 10) & 3, l = idx >> 12;
        const int g = lane >> 4, row = 16 * t + (lane & 15), k = 32 * s + 8 * g + jj;
        whfrag[idx] = f2bf(W_h[(l * H + k) * H + row]);
    }
    for (int idx = gid; idx < 4 * 2 * 64 * 8; idx += 8192) {
        const int jj = idx & 7, lane = (idx >> 3) & 63, s = (idx >> 9) & 1, t = idx >> 10;
        const int g = lane >> 4, row = 16 * t + (lane & 15), k = 32 * s + 8 * g + jj;
        wpffrag[idx] = f2bf(W_pf[k * SEL + row]);
    }
}

// ---------------------------------------------------------------------------
// Per-(b,k) object setup: objf A-frag (affinity, 16x16x32) + folded tab A-frag
// (16x16x16: row = 2H dim j, k-dim = object index; layout HW-verified in R3).
// ---------------------------------------------------------------------------
__global__ void setup_obj(const float* __restrict__ c, const float* __restrict__ t,
                          const float* __restrict__ W_of, const float* __restrict__ b_of,
                          const float* __restrict__ W_c1, const float* __restrict__ b_c1,
                          const float* __restrict__ W_c2, const float* __restrict__ b_c2,
                          const float* __restrict__ W_ss, const float* __restrict__ b_ss,
                          short* __restrict__ objffrag, short* __restrict__ tabfrag) {
    const int bk = blockIdx.x, b = bk >> 4, k = bk & 15;
    const int tid = threadIdx.x;                        // 0..127
    __shared__ float cwt[TE + DC];
    __shared__ float c1s[CD], c2s[CD];

    if (tid < 16) {
        float f   = __expf(-logf(10000.0f) * (float)tid * (1.0f / 15.0f));
        float arg = t[b] * f;
        cwt[tid]      = sinf(arg);
        cwt[tid + 16] = cosf(arg);
    }
    cwt[TE + tid] = c[(b * KK + k) * DC + tid];
    __syncthreads();

    if (tid < SEL) {   // object_features -> A-frag rows = object k, k-dim = tid
        float a = b_of[tid];
        for (int d = 0; d < TE + DC; ++d) a += cwt[d] * W_of[d * SEL + tid];
        a = swish_f(a);
        const int s = tid >> 5, g = (tid >> 3) & 3, jj = tid & 7;
        objffrag[(((b * 2 + s) * 64) + (16 * g + k)) * 8 + jj] = f2bf(a);
    }
    {
        float a = b_c1[tid];
        for (int d = 0; d < TE + DC; ++d) a += cwt[d] * W_c1[d * CD + tid];
        c1s[tid] = swish_f(a);
    }
    __syncthreads();
    {
        float a = b_c2[tid];
        for (int d = 0; d < CD; ++d) a += c1s[d] * W_c2[d * CD + tid];
        c2s[tid] = swish_f(a);
    }
    __syncthreads();

    // tab[l][j=tid] = c2 @ W_ss[l,:,j] + b_ss[l,j]
    // A-frag (16x16x16): u=j>>4, row=j&15, lane=16*(k>>2)+row, jj=k&3
    const int u = tid >> 4, row = tid & 15, lane = 16 * (k >> 2) + row, jj = k & 3;
    for (int l = 0; l < L; ++l) {
        const float* W = W_ss + l * CD * (2 * H);
        float a = b_ss[l * (2 * H) + tid];
        for (int d = 0; d < CD; ++d) a += c2s[d] * W[d * (2 * H) + tid];
        tabfrag[(((b * 6 + l) * 8 + u) * 64 + lane) * 4 + jj] = f2bf(a);
    }
}

// ---------------------------------------------------------------------------
// Main: 2048 blocks x 256 threads (4 waves), 2 point-tiles per wave (128
// points/block), ZERO barriers (hlds wave-exclusive). Layer-loop live set
// ~130 regs < 168 budget at __launch_bounds__(256,3) -> no spills (R5's 41 MB
// residual FETCH was spill traffic from the 4-tile/K32-padded live set).
// ---------------------------------------------------------------------------
__global__ __launch_bounds__(256, 3) void main_kernel(
    const float* __restrict__ x,
    const float* __restrict__ W_emb, const float* __restrict__ b_emb,
    const float* __restrict__ b_pf,  const float* __restrict__ b_h,
    const float* __restrict__ ln_g,  const float* __restrict__ ln_b,
    const float* __restrict__ W_out, const float* __restrict__ b_out,
    const short* __restrict__ objffrag, const short* __restrict__ tabfrag,
    const short* __restrict__ whfrag,   const short* __restrict__ wpffrag,
    float* __restrict__ out) {

    __shared__ short hlds[128 * 72];        // [point][dim], stride 72 shorts

    const int tid  = threadIdx.x;
    const int wave = tid >> 6, lane = tid & 63;
    const int p = lane & 15, g = lane >> 4;
    const int b = blockIdx.x >> 6;                  // 64 blocks / batch
    const int point0 = (blockIdx.x & 63) << 7;      // 128 points / block

    bf16x8 wpfr[4][2], objr[2];
#pragma unroll
    for (int t = 0; t < 4; ++t)
#pragma unroll
        for (int s = 0; s < 2; ++s)
            wpfr[t][s] = *(const bf16x8*)&wpffrag[(((t * 2 + s) * 64) + lane) * 8];
#pragma unroll
    for (int s = 0; s < 2; ++s)
        objr[s] = *(const bf16x8*)&objffrag[(((b * 2 + s) * 64) + lane) * 8];

    bf16x4 swfrag[2];

    // ---------------- Phase A ----------------
#pragma unroll
    for (int i = 0; i < 2; ++i) {
        const int tloc = (wave * 2 + i) * 16 + p;
        const int ptg  = b * NN + point0 + tloc;
        const float x0 = x[ptg * 3 + 0], x1 = x[ptg * 3 + 1], x2 = x[ptg * 3 + 2];

        float  ev[2][8];
        bf16x8 eb[2];
#pragma unroll
        for (int s = 0; s < 2; ++s)
#pragma unroll
            for (int jj = 0; jj < 8; ++jj) {
                const int k = 32 * s + 8 * g + jj;
                float e = b_emb[k] + x0 * W_emb[k] + x1 * W_emb[H + k] + x2 * W_emb[2 * H + k];
                ev[s][jj] = e;
                eb[s][jj] = f2bf(e);
            }

        // pf matvec, bias folded into C-init
        f32x4 macc[4];
#pragma unroll
        for (int t = 0; t < 4; ++t) {
            const float4 bp = *(const float4*)&b_pf[16 * t + 4 * g];
            f32x4 m; m[0] = bp.x; m[1] = bp.y; m[2] = bp.z; m[3] = bp.w;
            m = MFMA32(wpfr[t][0], eb[0], m);
            m = MFMA32(wpfr[t][1], eb[1], m);
            macc[t] = m;
        }
#pragma unroll
        for (int t = 0; t < 4; ++t) {
            short4 w;
            w.x = f2bf(swish_f(macc[t][0]));
            w.y = f2bf(swish_f(macc[t][1]));
            w.z = f2bf(swish_f(macc[t][2]));
            w.w = f2bf(swish_f(macc[t][3]));
            *(short4*)&hlds[tloc * 72 + 16 * t + 4 * g] = w;
        }
        bf16x8 pfb[2];
#pragma unroll
        for (int s = 0; s < 2; ++s)
            pfb[s] = *(bf16x8*)&hlds[tloc * 72 + 32 * s + 8 * g];

        // affinity: C[obj=4g+r][point=p]
        f32x4 aacc = {0.f, 0.f, 0.f, 0.f};
#pragma unroll
        for (int s = 0; s < 2; ++s)
            aacc = MFMA32(objr[s], pfb[s], aacc);

        // softmax over 16 objects
        float mx = fmaxf(fmaxf(aacc[0], aacc[1]), fmaxf(aacc[2], aacc[3]));
        mx = fmaxf(mx, __shfl_xor(mx, 16));
        mx = fmaxf(mx, __shfl_xor(mx, 32));
        float swv[4], ss = 0.f;
#pragma unroll
        for (int r = 0; r < 4; ++r) { swv[r] = __expf(aacc[r] - mx); ss += swv[r]; }
        ss += __shfl_xor(ss, 16);
        ss += __shfl_xor(ss, 32);
        const float inv = __builtin_amdgcn_rcpf(ss);

        // softmax C-layout (obj=4g+r) IS the 16x16x16 B-frag layout (k=4g+jj)
        bf16x4 sf;
#pragma unroll
        for (int r = 0; r < 4; ++r) sf[r] = f2bf(swv[r] * inv);
        swfrag[i] = sf;

        // h0 = swish(x_embed) in B-frag positions
#pragma unroll
        for (int s = 0; s < 2; ++s) {
            bf16x8 hb;
#pragma unroll
            for (int jj = 0; jj < 8; ++jj) hb[jj] = f2bf(swish_f(ev[s][jj]));
            *(bf16x8*)&hlds[tloc * 72 + 32 * s + 8 * g] = hb;
        }
    }

    // ---------------- AdaLN layers (no barriers) ----------------
    for (int l = 0; l < L; ++l) {
        bf16x8 whr[4][2];
        bf16x4 tabr[8];
#pragma unroll
        for (int t = 0; t < 4; ++t)
#pragma unroll
            for (int s = 0; s < 2; ++s)
                whr[t][s] = *(const bf16x8*)&whfrag[((l * 8 + t * 2 + s) * 64 + lane) * 8];
#pragma unroll
        for (int u = 0; u < 8; ++u)
            tabr[u] = *(const bf16x4*)&tabfrag[(((b * 6 + l) * 8 + u) * 64 + lane) * 4];

#pragma unroll
        for (int i = 0; i < 2; ++i) {
            const int tloc = (wave * 2 + i) * 16 + p;
            const bf16x8 hb0 = *(bf16x8*)&hlds[tloc * 72 + 8 * g];
            const bf16x8 hb1 = *(bf16x8*)&hlds[tloc * 72 + 32 + 8 * g];
            const bf16x4 sf  = swfrag[i];

            // scale part of sel-mix (u=0..3)
            f32x4 sca[4];
#pragma unroll
            for (int u = 0; u < 4; ++u) {
                f32x4 z = {0.f, 0.f, 0.f, 0.f};
                sca[u] = MFMA16(tabr[u], sf, z);
            }

            // matvec, bias folded into C-init
            f32x4 macc[4];
#pragma unroll
            for (int t = 0; t < 4; ++t) {
                const float4 bh = *(const float4*)&b_h[l * H + 16 * t + 4 * g];
                f32x4 m; m[0] = bh.x; m[1] = bh.y; m[2] = bh.z; m[3] = bh.w;
                m = MFMA32(whr[t][0], hb0, m);
                m = MFMA32(whr[t][1], hb1, m);
                macc[t] = m;
            }

            float hn[4][4], s1 = 0.f, s2 = 0.f;
#pragma unroll
            for (int t = 0; t < 4; ++t)
#pragma unroll
                for (int r = 0; r < 4; ++r) {
                    const float v = swish_f(macc[t][r]);
                    hn[t][r] = v; s1 += v; s2 += v * v;
                }
            s1 += __shfl_xor(s1, 16); s1 += __shfl_xor(s1, 32);
            s2 += __shfl_xor(s2, 16); s2 += __shfl_xor(s2, 32);
            const float mu  = s1 * (1.0f / 64.0f);
            const float var = s2 * (1.0f / 64.0f) - mu * mu;
            const float rin = rsqrtf(var + EPSV);

            // shift part of sel-mix (u=4..7), issued just before the apply
            f32x4 sha[4];
#pragma unroll
            for (int u = 0; u < 4; ++u) {
                f32x4 z = {0.f, 0.f, 0.f, 0.f};
                sha[u] = MFMA16(tabr[4 + u], sf, z);
            }

            if (l < L - 1) {
#pragma unroll
                for (int t = 0; t < 4; ++t) {
                    const float4 gg = *(const float4*)&ln_g[l * H + 16 * t + 4 * g];
                    const float4 bb = *(const float4*)&ln_b[l * H + 16 * t + 4 * g];
                    float ggv[4]; ggv[0] = gg.x; ggv[1] = gg.y; ggv[2] = gg.z; ggv[3] = gg.w;
                    float bbv[4]; bbv[0] = bb.x; bbv[1] = bb.y; bbv[2] = bb.z; bbv[3] = bb.w;
                    short wv[4];
#pragma unroll
                    for (int r = 0; r < 4; ++r) {
                        const float lnv = (hn[t][r] - mu) * rin * ggv[r] + bbv[r];
                        wv[r] = f2bf(lnv * (1.0f + sca[t][r]) + sha[t][r]);
                    }
                    short4 w; w.x = wv[0]; w.y = wv[1]; w.z = wv[2]; w.w = wv[3];
                    *(short4*)&hlds[tloc * 72 + 16 * t + 4 * g] = w;
                }
            } else {
                float d0 = 0.f, d1 = 0.f, d2 = 0.f;
#pragma unroll
                for (int t = 0; t < 4; ++t) {
                    const float4 gg = *(const float4*)&ln_g[l * H + 16 * t + 4 * g];
                    const float4 bb = *(const float4*)&ln_b[l * H + 16 * t + 4 * g];
                    float ggv[4]; ggv[0] = gg.x; ggv[1] = gg.y; ggv[2] = gg.z; ggv[3] = gg.w;
                    float bbv[4]; bbv[0] = bb.x; bbv[1] = bb.y; bbv[2] = bb.z; bbv[3] = bb.w;
                    const float4 w0 = *(const float4*)&W_out[(16 * t + 4 * g) * 3];
                    const float4 w1 = *(const float4*)&W_out[(16 * t + 4 * g) * 3 + 4];
                    const float4 w2 = *(const float4*)&W_out[(16 * t + 4 * g) * 3 + 8];
                    float wv[12];
                    wv[0] = w0.x; wv[1] = w0.y; wv[2]  = w0.z; wv[3]  = w0.w;
                    wv[4] = w1.x; wv[5] = w1.y; wv[6]  = w1.z; wv[7]  = w1.w;
                    wv[8] = w2.x; wv[9] = w2.y; wv[10] = w2.z; wv[11] = w2.w;
#pragma unroll
                    for (int r = 0; r < 4; ++r) {
                        const float lnv = (hn[t][r] - mu) * rin * ggv[r] + bbv[r];
                        const float hv  = lnv * (1.0f + sca[t][r]) + sha[t][r];
                        d0 += hv * wv[r * 3 + 0];
                        d1 += hv * wv[r * 3 + 1];
                        d2 += hv * wv[r * 3 + 2];
                    }
                }
                d0 += __shfl_xor(d0, 16); d0 += __shfl_xor(d0, 32);
                d1 += __shfl_xor(d1, 16); d1 += __shfl_xor(d1, 32);
                d2 += __shfl_xor(d2, 16); d2 += __shfl_xor(d2, 32);
                if (g == 0) {
                    const int ptg = b * NN + point0 + tloc;
                    out[ptg * 3 + 0] = d0 + b_out[0];
                    out[ptg * 3 + 1] = d1 + b_out[1];
                    out[ptg * 3 + 2] = d2 + b_out[2];
                }
            }
        }
    }
}

extern "C" void kernel_launch(void* const* d_in, const int* in_sizes, int n_in,
                              void* d_out, int out_size, void* d_ws, size_t ws_size,
                              hipStream_t stream) {
    const float* x     = (const float*)d_in[0];
    const float* c     = (const float*)d_in[1];
    const float* t     = (const float*)d_in[2];
    const float* W_emb = (const float*)d_in[3];
    const float* b_emb = (const float*)d_in[4];
    const float* W_pf  = (const float*)d_in[5];
    const float* b_pf  = (const float*)d_in[6];
    const float* W_of  = (const float*)d_in[7];
    const float* b_of  = (const float*)d_in[8];
    const float* W_c1  = (const float*)d_in[9];
    const float* b_c1  = (const float*)d_in[10];
    const float* W_c2  = (const float*)d_in[11];
    const float* b_c2  = (const float*)d_in[12];
    const float* W_h   = (const float*)d_in[13];
    const float* b_h   = (const float*)d_in[14];
    const float* W_ss  = (const float*)d_in[15];
    const float* b_ss  = (const float*)d_in[16];
    const float* ln_g  = (const float*)d_in[17];
    const float* ln_b  = (const float*)d_in[18];
    const float* W_out = (const float*)d_in[19];
    const float* b_out = (const float*)d_in[20];
    float* out = (float*)d_out;

    short* wsb      = (short*)d_ws;
    short* objffrag = wsb + OFF_OBJF;
    short* tabfrag  = wsb + OFF_TAB;
    short* whfrag   = wsb + OFF_WH;
    short* wpffrag  = wsb + OFF_WPF;

    setup_w<<<32, 256, 0, stream>>>(W_h, W_pf, whfrag, wpffrag);
    setup_obj<<<BB * KK, 128, 0, stream>>>(c, t, W_of, b_of, W_c1, b_c1,
                                           W_c2, b_c2, W_ss, b_ss, objffrag, tabfrag);
    main_kernel<<<2048, 256, 0, stream>>>(x, W_emb, b_emb, b_pf, b_h, ln_g, ln_b,
                                          W_out, b_out, objffrag, tabfrag,
                                          whfrag, wpffrag, out);
}